// Round 1
// baseline (1359.940 us; speedup 1.0000x reference)
//
#include <hip/hip_runtime.h>
#include <cstdint>

#define NB 32      // batch
#define TIN 64
#define TOUT 64
#define EMB 256
#define DU 512
#define VSZ 32000
#define BT 2048    // NB*TOUT
#define G4 2048    // 4*DU
#define KL 768     // DU+EMB

typedef __attribute__((ext_vector_type(4))) float f32x4;
typedef __attribute__((ext_vector_type(8))) short s16x8;

__device__ __forceinline__ unsigned short f2bf(float f){
  unsigned int u = __float_as_uint(f);
  u += 0x7fffu + ((u >> 16) & 1u);
  return (unsigned short)(u >> 16);
}

// ---------------- embedding gather + cast ----------------
__global__ void k_embed(const int* __restrict__ toks, const float* __restrict__ emb,
                        unsigned short* __restrict__ x_bf, unsigned short* __restrict__ lstmin){
  int idx = blockIdx.x * 256 + threadIdx.x;   // 0..BT*EMB-1
  int row = idx >> 8, e = idx & 255;
  int tok = toks[row];
  unsigned short h = f2bf(emb[tok * EMB + e]);
  x_bf[row * EMB + e] = h;
  lstmin[row * KL + DU + e] = h;   // x occupies cols [DU, DU+EMB)
}

// ---------------- enc cast + per-batch transpose ----------------
__global__ void k_enccast(const float* __restrict__ enc, unsigned short* __restrict__ enc_bf,
                          unsigned short* __restrict__ encT){
  int b = blockIdx.z, dt = blockIdx.x, st = blockIdx.y;
  __shared__ float tile[32][33];
  int tx = threadIdx.x & 31, ty = threadIdx.x >> 5;
  const float* eb = enc + b * TIN * DU;
  #pragma unroll
  for (int i = 0; i < 4; i++){
    int s = st*32 + ty + i*8, d = dt*32 + tx;
    float v = eb[s * DU + d];
    tile[ty + i*8][tx] = v;
    enc_bf[(b * TIN + s) * DU + d] = f2bf(v);
  }
  __syncthreads();
  #pragma unroll
  for (int i = 0; i < 4; i++){
    int d = dt*32 + ty + i*8, s = st*32 + tx;
    encT[(b * DU + d) * TIN + s] = f2bf(tile[tx][ty + i*8]);
  }
}

// ---------------- fp32 [R][C] -> bf16 [C][R] transpose ----------------
__global__ void k_transpose(const float* __restrict__ in, unsigned short* __restrict__ out, int R, int C){
  __shared__ float tile[32][33];
  int tx = threadIdx.x & 31, ty = threadIdx.x >> 5;
  int c0 = blockIdx.x * 32, r0 = blockIdx.y * 32;
  #pragma unroll
  for (int i = 0; i < 4; i++) tile[ty + i*8][tx] = in[(r0 + ty + i*8) * C + c0 + tx];
  __syncthreads();
  #pragma unroll
  for (int i = 0; i < 4; i++) out[(c0 + ty + i*8) * R + r0 + tx] = f2bf(tile[tx][ty + i*8]);
}

// ---------------- generic bf16 GEMM: C[M,N] = A[M,K] * Bt[N,K]^T (+bias) ----------------
template<bool OUT_BF16, bool BIAS>
__global__ __launch_bounds__(256) void k_gemm_bt(const unsigned short* __restrict__ A,
                                                 const unsigned short* __restrict__ Bt,
                                                 const float* __restrict__ bias,
                                                 void* __restrict__ Cout, int M, int N, int K){
  __shared__ unsigned short As[128][72];
  __shared__ unsigned short Bs[128][72];
  const int tid = threadIdx.x;
  const int wave = tid >> 6, lane = tid & 63;
  const int l15 = lane & 15, quad = lane >> 4;
  const int m_base = blockIdx.y * 128, n_base = blockIdx.x * 128;
  const int wr = wave >> 1, wc = wave & 1;
  f32x4 acc[4][4] = {};
  const int srow = tid >> 3, schunk = (tid & 7) * 8;
  for (int k0 = 0; k0 < K; k0 += 64){
    #pragma unroll
    for (int rr = 0; rr < 4; rr++){
      int r = rr * 32 + srow;
      *(s16x8*)&As[r][schunk] = *(const s16x8*)&A[(m_base + r) * K + k0 + schunk];
      *(s16x8*)&Bs[r][schunk] = *(const s16x8*)&Bt[(n_base + r) * K + k0 + schunk];
    }
    __syncthreads();
    #pragma unroll
    for (int ks = 0; ks < 2; ks++){
      s16x8 af[4], bfm[4];
      #pragma unroll
      for (int mt = 0; mt < 4; mt++) af[mt]  = *(const s16x8*)&As[wr*64 + mt*16 + l15][ks*32 + quad*8];
      #pragma unroll
      for (int nt = 0; nt < 4; nt++) bfm[nt] = *(const s16x8*)&Bs[wc*64 + nt*16 + l15][ks*32 + quad*8];
      #pragma unroll
      for (int mt = 0; mt < 4; mt++)
        #pragma unroll
        for (int nt = 0; nt < 4; nt++)
          acc[mt][nt] = __builtin_amdgcn_mfma_f32_16x16x32_bf16(af[mt], bfm[nt], acc[mt][nt], 0, 0, 0);
    }
    __syncthreads();
  }
  float bv[4];
  #pragma unroll
  for (int nt = 0; nt < 4; nt++){
    int n = n_base + wc*64 + nt*16 + l15;
    bv[nt] = BIAS ? bias[n] : 0.f;
  }
  #pragma unroll
  for (int mt = 0; mt < 4; mt++){
    #pragma unroll
    for (int nt = 0; nt < 4; nt++){
      int n = n_base + wc*64 + nt*16 + l15;
      #pragma unroll
      for (int r = 0; r < 4; r++){
        int m = m_base + wr*64 + mt*16 + quad*4 + r;
        float v = acc[mt][nt][r] + bv[nt];
        if (OUT_BF16) ((unsigned short*)Cout)[m * N + n] = f2bf(v);
        else          ((float*)Cout)[m * N + n] = v;
      }
    }
  }
}

// ---------------- fused attention per batch: scores -> softmax -> att ----------------
__global__ __launch_bounds__(256) void k_attn(const unsigned short* __restrict__ q,
                                              const unsigned short* __restrict__ enc_bf,
                                              const unsigned short* __restrict__ encT,
                                              float* __restrict__ attn_out,
                                              unsigned short* __restrict__ lstmin){
  const int b = blockIdx.x;
  const int tid = threadIdx.x;
  const int wave = tid >> 6, lane = tid & 63;
  const int l15 = lane & 15, quad = lane >> 4;
  __shared__ unsigned short AB[2][64][136];   // phase1 A/B staging; phase2 reuses as B2[128][72]
  __shared__ float ss[64][66];
  __shared__ unsigned short Ps[64][72];

  // phase 1: scores[t][s] = sum_d q[t,d] * enc[s,d], K=512 in chunks of 128
  f32x4 acc[4] = {};
  for (int kc = 0; kc < 4; kc++){
    int k0 = kc * 128;
    #pragma unroll
    for (int i = 0; i < 4; i++){
      int idx = i * 256 + tid;
      int row = idx >> 4, ch = (idx & 15) * 8;
      *(s16x8*)&AB[0][row][ch] = *(const s16x8*)&q[(b*64 + row) * DU + k0 + ch];
      *(s16x8*)&AB[1][row][ch] = *(const s16x8*)&enc_bf[(b*64 + row) * DU + k0 + ch];
    }
    __syncthreads();
    #pragma unroll
    for (int ks = 0; ks < 4; ks++){
      s16x8 a = *(const s16x8*)&AB[0][wave*16 + l15][ks*32 + quad*8];
      #pragma unroll
      for (int nt = 0; nt < 4; nt++){
        s16x8 bb = *(const s16x8*)&AB[1][nt*16 + l15][ks*32 + quad*8];
        acc[nt] = __builtin_amdgcn_mfma_f32_16x16x32_bf16(a, bb, acc[nt], 0, 0, 0);
      }
    }
    __syncthreads();
  }
  #pragma unroll
  for (int nt = 0; nt < 4; nt++)
    #pragma unroll
    for (int r = 0; r < 4; r++)
      ss[wave*16 + quad*4 + r][nt*16 + l15] = acc[nt][r];
  __syncthreads();
  // softmax rows (64 threads, one row each)
  if (tid < 64){
    float mx = -1e30f;
    for (int s = 0; s < 64; s++) mx = fmaxf(mx, ss[tid][s]);
    float sum = 0.f;
    for (int s = 0; s < 64; s++){ float e = __expf(ss[tid][s] - mx); ss[tid][s] = e; sum += e; }
    float inv = 1.f / sum;
    for (int s = 0; s < 64; s++){
      float p = ss[tid][s] * inv;
      attn_out[(b*64 + tid) * 64 + s] = p;
      Ps[tid][s] = f2bf(p);
    }
  }
  __syncthreads();
  // phase 2: att[t][d] = sum_s P[t,s] * encT[d,s], d in chunks of 128
  unsigned short (*B2)[72] = (unsigned short (*)[72])AB;
  for (int dc = 0; dc < 4; dc++){
    #pragma unroll
    for (int i = 0; i < 4; i++){
      int idx = i * 256 + tid;
      int row = idx >> 3, ch = (idx & 7) * 8;
      *(s16x8*)&B2[row][ch] = *(const s16x8*)&encT[(b*DU + dc*128 + row) * TIN + ch];
    }
    __syncthreads();
    f32x4 acc2[8] = {};
    #pragma unroll
    for (int ks = 0; ks < 2; ks++){
      s16x8 a = *(const s16x8*)&Ps[wave*16 + l15][ks*32 + quad*8];
      #pragma unroll
      for (int nt = 0; nt < 8; nt++){
        s16x8 bb = *(const s16x8*)&B2[nt*16 + l15][ks*32 + quad*8];
        acc2[nt] = __builtin_amdgcn_mfma_f32_16x16x32_bf16(a, bb, acc2[nt], 0, 0, 0);
      }
    }
    #pragma unroll
    for (int nt = 0; nt < 8; nt++){
      int d = dc*128 + nt*16 + l15;
      #pragma unroll
      for (int r = 0; r < 4; r++){
        int t = wave*16 + quad*4 + r;
        lstmin[(b*64 + t) * KL + d] = f2bf(acc2[nt][r]);
      }
    }
    __syncthreads();
  }
}

// ---------------- sequential LSTM: 64 WGs, per-step grid barrier ----------------
// WG wg owns hidden cols j0=wg*8..+7 (z cols g*512+j0+jj for 4 gates). Wh slice lives
// swizzled in LDS for all 64 steps; h is double-buffered bf16 in global memory.
__global__ __launch_bounds__(256) void k_lstm(const float* __restrict__ Z, const float* __restrict__ Wh,
                                              const float* __restrict__ h0, const float* __restrict__ c0,
                                              unsigned short* __restrict__ hbuf, unsigned short* __restrict__ hs,
                                              float* __restrict__ out_h, float* __restrict__ out_c,
                                              unsigned int* __restrict__ cnt){
  const int wg = blockIdx.x;
  const int j0 = wg * 8;
  const int tid = threadIdx.x, wave = tid >> 6, lane = tid & 63;
  const int l15 = lane & 15, quad = lane >> 4;
  __shared__ unsigned short Whs[32][512];  // row ln=g*8+jj; 16B chunk kc stored at kc^(ln&7)
  __shared__ float zs[32][36];

  { // load + transpose + swizzle Wh slice (one-time)
    int c = tid & 31, kb = tid >> 5;
    int g = c >> 3, jj = c & 7;
    int col = g * DU + j0 + jj;
    for (int it = 0; it < 64; it++){
      int k = it * 8 + kb;
      unsigned short v = f2bf(Wh[k * G4 + col]);
      int kcs = (k >> 3) ^ (c & 7);
      Whs[c][kcs * 8 + (k & 7)] = v;
    }
  }
  const int gb = tid >> 3, gj = tid & 7;
  float creg = c0[gb * DU + j0 + gj];
  __syncthreads();

  const int m0 = (wave & 1) * 16, n0 = (wave >> 1) * 16;
  const int ln = n0 + l15;
  const int gg = ln >> 3, gjj = ln & 7;
  const int zcol = gg * DU + j0 + gjj;

  for (int t = 0; t < 64; t++){
    f32x4 acc = {};
    if (t == 0){
      #pragma unroll
      for (int ks = 0; ks < 16; ks++){
        const float* hp = h0 + (m0 + l15) * DU + ks*32 + quad*8;
        unsigned short tmp[8];
        #pragma unroll
        for (int j = 0; j < 8; j++) tmp[j] = f2bf(hp[j]);
        s16x8 a = *(s16x8*)tmp;
        int kcs = (ks*4 + quad) ^ (ln & 7);
        s16x8 bb = *(const s16x8*)&Whs[ln][kcs * 8];
        acc = __builtin_amdgcn_mfma_f32_16x16x32_bf16(a, bb, acc, 0, 0, 0);
      }
    } else {
      const unsigned short* hcur = hbuf + (t & 1) * NB * DU;
      #pragma unroll
      for (int ks = 0; ks < 16; ks++){
        s16x8 a = *(const s16x8*)&hcur[(m0 + l15) * DU + ks*32 + quad*8];
        int kcs = (ks*4 + quad) ^ (ln & 7);
        s16x8 bb = *(const s16x8*)&Whs[ln][kcs * 8];
        acc = __builtin_amdgcn_mfma_f32_16x16x32_bf16(a, bb, acc, 0, 0, 0);
      }
    }
    #pragma unroll
    for (int r = 0; r < 4; r++){
      int bb_ = m0 + quad*4 + r;
      zs[bb_][ln] = acc[r] + Z[(bb_ * 64 + t) * G4 + zcol];
    }
    __syncthreads();
    { // gates: one (b, jj) per thread
      float zi = zs[gb][0 + gj], zf = zs[gb][8 + gj], zg = zs[gb][16 + gj], zo = zs[gb][24 + gj];
      float gi = 1.f / (1.f + __expf(-zi));
      float gf = 1.f / (1.f + __expf(-zf));
      float e2 = __expf(2.f * zg); float gc = (e2 - 1.f) / (e2 + 1.f);
      float go = 1.f / (1.f + __expf(-zo));
      creg = gf * creg + gi * gc;
      float ec = __expf(2.f * creg); float tc = (ec - 1.f) / (ec + 1.f);
      float h = go * tc;
      unsigned short hb = f2bf(h);
      hbuf[((t + 1) & 1) * NB * DU + gb * DU + j0 + gj] = hb;
      hs[(gb * 64 + t) * DU + j0 + gj] = hb;
      if (t == 63){ out_h[gb * DU + j0 + gj] = h; out_c[gb * DU + j0 + gj] = creg; }
    }
    if (t < 63){ // grid barrier
      __threadfence();
      __syncthreads();
      if (tid == 0){
        __hip_atomic_fetch_add(cnt, 1u, __ATOMIC_ACQ_REL, __HIP_MEMORY_SCOPE_AGENT);
        unsigned int target = 64u * (unsigned)(t + 1);
        while (__hip_atomic_load(cnt, __ATOMIC_ACQUIRE, __HIP_MEMORY_SCOPE_AGENT) < target)
          __builtin_amdgcn_s_sleep(2);
      }
      __syncthreads();
      __threadfence();
    }
  }
}

extern "C" void kernel_launch(void* const* d_in, const int* in_sizes, int n_in,
                              void* d_out, int out_size, void* d_ws, size_t ws_size,
                              hipStream_t stream) {
  const int*   toks   = (const int*)  d_in[0];
  const float* enc    = (const float*)d_in[1];
  const float* h0     = (const float*)d_in[2];
  const float* c0     = (const float*)d_in[3];
  const float* emb    = (const float*)d_in[4];
  const float* Wq     = (const float*)d_in[5];
  const float* bq     = (const float*)d_in[6];
  const float* Wx     = (const float*)d_in[7];
  const float* Wh     = (const float*)d_in[8];
  const float* b_lstm = (const float*)d_in[9];
  const float* Wfc    = (const float*)d_in[10];
  const float* bfc    = (const float*)d_in[11];

  float* out_logits = (float*)d_out;
  float* out_h    = out_logits + (size_t)BT * VSZ;          // 65,536,000
  float* out_c    = out_h + NB * DU;
  float* out_attn = out_c + NB * DU;

  char* ws = (char*)d_ws;
  size_t off = 0;
  auto take = [&](size_t bytes){ void* p = ws + off; off += (bytes + 255) & ~(size_t)255; return p; };
  unsigned int*   cnt    = (unsigned int*)  take(256);
  unsigned short* x_bf   = (unsigned short*)take((size_t)BT * EMB * 2);
  unsigned short* lstmin = (unsigned short*)take((size_t)BT * KL * 2);
  unsigned short* q_bf   = (unsigned short*)take((size_t)BT * DU * 2);
  unsigned short* enc_bf = (unsigned short*)take((size_t)NB * TIN * DU * 2);
  unsigned short* encT   = (unsigned short*)take((size_t)NB * DU * TIN * 2);
  unsigned short* Wq_t   = (unsigned short*)take((size_t)DU * EMB * 2);
  unsigned short* Wx_t   = (unsigned short*)take((size_t)G4 * KL * 2);
  unsigned short* Wfc_t  = (unsigned short*)take((size_t)VSZ * DU * 2);
  float*          Zbuf   = (float*)         take((size_t)BT * G4 * 4);
  unsigned short* hbuf   = (unsigned short*)take((size_t)2 * NB * DU * 2);
  unsigned short* hs     = (unsigned short*)take((size_t)BT * DU * 2);

  hipMemsetAsync(cnt, 0, 256, stream);

  k_embed<<<BT * EMB / 256, 256, 0, stream>>>(toks, emb, x_bf, lstmin);
  k_enccast<<<dim3(DU/32, TIN/32, NB), 256, 0, stream>>>(enc, enc_bf, encT);
  k_transpose<<<dim3(DU/32, EMB/32), 256, 0, stream>>>(Wq, Wq_t, EMB, DU);
  k_transpose<<<dim3(G4/32, KL/32), 256, 0, stream>>>(Wx, Wx_t, KL, G4);
  k_transpose<<<dim3(VSZ/32, DU/32), 256, 0, stream>>>(Wfc, Wfc_t, DU, VSZ);

  // q = x @ Wq + bq  -> bf16
  k_gemm_bt<true, true><<<dim3(DU/128, BT/128), 256, 0, stream>>>(x_bf, Wq_t, bq, q_bf, BT, DU, EMB);
  // attention: scores/softmax/att -> lstmin cols [0,DU), attn_w -> d_out
  k_attn<<<NB, 256, 0, stream>>>(q_bf, enc_bf, encT, out_attn, lstmin);
  // Z = lstm_in @ Wx + b_lstm  -> fp32
  k_gemm_bt<false, true><<<dim3(G4/128, BT/128), 256, 0, stream>>>(lstmin, Wx_t, b_lstm, Zbuf, BT, G4, KL);
  // sequential LSTM
  k_lstm<<<64, 256, 0, stream>>>(Zbuf, Wh, h0, c0, hbuf, hs, out_h, out_c, cnt);
  // logits = hs @ Wfc + bfc -> fp32 d_out
  k_gemm_bt<false, true><<<dim3(VSZ/128, BT/128), 256, 0, stream>>>(hs, Wfc_t, bfc, out_logits, BT, VSZ, DU);
}

// Round 2
// 753.071 us; speedup vs baseline: 1.8059x; 1.8059x over previous
//
#include <hip/hip_runtime.h>
#include <cstdint>

#define NB 32      // batch
#define TIN 64
#define TOUT 64
#define EMB 256
#define DU 512
#define VSZ 32000
#define BT 2048    // NB*TOUT
#define G4 2048    // 4*DU
#define KL 768     // DU+EMB

typedef __attribute__((ext_vector_type(4))) float f32x4;
typedef __attribute__((ext_vector_type(8))) short s16x8;

__device__ __forceinline__ unsigned short f2bf(float f){
  unsigned int u = __float_as_uint(f);
  u += 0x7fffu + ((u >> 16) & 1u);
  return (unsigned short)(u >> 16);
}

// ---------------- embedding gather + cast ----------------
__global__ void k_embed(const int* __restrict__ toks, const float* __restrict__ emb,
                        unsigned short* __restrict__ x_bf, unsigned short* __restrict__ lstmin){
  int idx = blockIdx.x * 256 + threadIdx.x;   // 0..BT*EMB-1
  int row = idx >> 8, e = idx & 255;
  int tok = toks[row];
  unsigned short h = f2bf(emb[tok * EMB + e]);
  x_bf[row * EMB + e] = h;
  lstmin[row * KL + DU + e] = h;   // x occupies cols [DU, DU+EMB)
}

// ---------------- h0 fp32 -> bf16 into hbuf slot 0 ----------------
__global__ void k_h0cast(const float* __restrict__ h0, unsigned short* __restrict__ hbuf){
  int i = blockIdx.x * 256 + threadIdx.x;
  hbuf[i] = f2bf(h0[i]);
}

// ---------------- enc cast + per-batch transpose ----------------
__global__ void k_enccast(const float* __restrict__ enc, unsigned short* __restrict__ enc_bf,
                          unsigned short* __restrict__ encT){
  int b = blockIdx.z, dt = blockIdx.x, st = blockIdx.y;
  __shared__ float tile[32][33];
  int tx = threadIdx.x & 31, ty = threadIdx.x >> 5;
  const float* eb = enc + b * TIN * DU;
  #pragma unroll
  for (int i = 0; i < 4; i++){
    int s = st*32 + ty + i*8, d = dt*32 + tx;
    float v = eb[s * DU + d];
    tile[ty + i*8][tx] = v;
    enc_bf[(b * TIN + s) * DU + d] = f2bf(v);
  }
  __syncthreads();
  #pragma unroll
  for (int i = 0; i < 4; i++){
    int d = dt*32 + ty + i*8, s = st*32 + tx;
    encT[(b * DU + d) * TIN + s] = f2bf(tile[tx][ty + i*8]);
  }
}

// ---------------- fp32 [R][C] -> bf16 [C][R] transpose ----------------
__global__ void k_transpose(const float* __restrict__ in, unsigned short* __restrict__ out, int R, int C){
  __shared__ float tile[32][33];
  int tx = threadIdx.x & 31, ty = threadIdx.x >> 5;
  int c0 = blockIdx.x * 32, r0 = blockIdx.y * 32;
  #pragma unroll
  for (int i = 0; i < 4; i++) tile[ty + i*8][tx] = in[(r0 + ty + i*8) * C + c0 + tx];
  __syncthreads();
  #pragma unroll
  for (int i = 0; i < 4; i++) out[(c0 + ty + i*8) * R + r0 + tx] = f2bf(tile[tx][ty + i*8]);
}

// ---------------- generic bf16 GEMM (padded-LDS variant): C[M,N]=A[M,K]*Bt[N,K]^T ----------------
template<bool OUT_BF16, bool BIAS>
__global__ __launch_bounds__(256) void k_gemm_bt(const unsigned short* __restrict__ A,
                                                 const unsigned short* __restrict__ Bt,
                                                 const float* __restrict__ bias,
                                                 void* __restrict__ Cout, int M, int N, int K){
  __shared__ unsigned short As[128][72];
  __shared__ unsigned short Bs[128][72];
  const int tid = threadIdx.x;
  const int wave = tid >> 6, lane = tid & 63;
  const int l15 = lane & 15, quad = lane >> 4;
  const int m_base = blockIdx.y * 128, n_base = blockIdx.x * 128;
  const int wr = wave >> 1, wc = wave & 1;
  f32x4 acc[4][4] = {};
  const int srow = tid >> 3, schunk = (tid & 7) * 8;
  for (int k0 = 0; k0 < K; k0 += 64){
    #pragma unroll
    for (int rr = 0; rr < 4; rr++){
      int r = rr * 32 + srow;
      *(s16x8*)&As[r][schunk] = *(const s16x8*)&A[(size_t)(m_base + r) * K + k0 + schunk];
      *(s16x8*)&Bs[r][schunk] = *(const s16x8*)&Bt[(size_t)(n_base + r) * K + k0 + schunk];
    }
    __syncthreads();
    #pragma unroll
    for (int ks = 0; ks < 2; ks++){
      s16x8 af[4], bfm[4];
      #pragma unroll
      for (int mt = 0; mt < 4; mt++) af[mt]  = *(const s16x8*)&As[wr*64 + mt*16 + l15][ks*32 + quad*8];
      #pragma unroll
      for (int nt = 0; nt < 4; nt++) bfm[nt] = *(const s16x8*)&Bs[wc*64 + nt*16 + l15][ks*32 + quad*8];
      #pragma unroll
      for (int mt = 0; mt < 4; mt++)
        #pragma unroll
        for (int nt = 0; nt < 4; nt++)
          acc[mt][nt] = __builtin_amdgcn_mfma_f32_16x16x32_bf16(af[mt], bfm[nt], acc[mt][nt], 0, 0, 0);
    }
    __syncthreads();
  }
  #pragma unroll
  for (int mt = 0; mt < 4; mt++){
    #pragma unroll
    for (int nt = 0; nt < 4; nt++){
      int n = n_base + wc*64 + nt*16 + l15;
      float bv = BIAS ? bias[n] : 0.f;
      #pragma unroll
      for (int r = 0; r < 4; r++){
        int m = m_base + wr*64 + mt*16 + quad*4 + r;
        float v = acc[mt][nt][r] + bv;
        if (OUT_BF16) ((unsigned short*)Cout)[(size_t)m * N + n] = f2bf(v);
        else          ((float*)Cout)[(size_t)m * N + n] = v;
      }
    }
  }
}

// ---------------- m97-style GEMM for logits: global_load_lds staging, unpadded LDS ----------------
__global__ __launch_bounds__(256) void k_gemm_lds(const unsigned short* __restrict__ A,
                                                  const unsigned short* __restrict__ Bt,
                                                  const float* __restrict__ bias,
                                                  float* __restrict__ Cout, int M, int N, int K){
  __shared__ unsigned short As[128 * 64];
  __shared__ unsigned short Bs[128 * 64];
  const int tid = threadIdx.x;
  const int wave = tid >> 6, lane = tid & 63;
  const int l15 = lane & 15, quad = lane >> 4;
  const int m_base = blockIdx.y * 128, n_base = blockIdx.x * 128;
  const int wr = wave >> 1, wc = wave & 1;
  f32x4 acc[4][4] = {};
  const int srow = lane >> 3;        // 0..7 row within 8-row stripe
  const int scol = (lane & 7) * 8;   // short offset of 16B chunk
  for (int k0 = 0; k0 < K; k0 += 64){
    #pragma unroll
    for (int i = 0; i < 4; i++){
      int ra = wave * 32 + i * 8;    // stripe base row (wave-uniform)
      const unsigned short* ga = &A [(size_t)(m_base + ra + srow) * K + k0 + scol];
      const unsigned short* gb = &Bt[(size_t)(n_base + ra + srow) * K + k0 + scol];
      __builtin_amdgcn_global_load_lds((const __attribute__((address_space(1))) unsigned int*)ga,
                                       (__attribute__((address_space(3))) unsigned int*)&As[ra * 64],
                                       16, 0, 0);
      __builtin_amdgcn_global_load_lds((const __attribute__((address_space(1))) unsigned int*)gb,
                                       (__attribute__((address_space(3))) unsigned int*)&Bs[ra * 64],
                                       16, 0, 0);
    }
    __syncthreads();
    #pragma unroll
    for (int ks = 0; ks < 2; ks++){
      s16x8 af[4], bfm[4];
      #pragma unroll
      for (int mt = 0; mt < 4; mt++) af[mt]  = *(const s16x8*)&As[(wr*64 + mt*16 + l15) * 64 + ks*32 + quad*8];
      #pragma unroll
      for (int nt = 0; nt < 4; nt++) bfm[nt] = *(const s16x8*)&Bs[(wc*64 + nt*16 + l15) * 64 + ks*32 + quad*8];
      #pragma unroll
      for (int mt = 0; mt < 4; mt++)
        #pragma unroll
        for (int nt = 0; nt < 4; nt++)
          acc[mt][nt] = __builtin_amdgcn_mfma_f32_16x16x32_bf16(af[mt], bfm[nt], acc[mt][nt], 0, 0, 0);
    }
    __syncthreads();
  }
  #pragma unroll
  for (int mt = 0; mt < 4; mt++){
    #pragma unroll
    for (int nt = 0; nt < 4; nt++){
      int n = n_base + wc*64 + nt*16 + l15;
      float bv = bias[n];
      #pragma unroll
      for (int r = 0; r < 4; r++){
        int m = m_base + wr*64 + mt*16 + quad*4 + r;
        Cout[(size_t)m * N + n] = acc[mt][nt][r] + bv;
      }
    }
  }
}

// ---------------- fused attention per batch: scores -> softmax -> att ----------------
__global__ __launch_bounds__(256) void k_attn(const unsigned short* __restrict__ q,
                                              const unsigned short* __restrict__ enc_bf,
                                              const unsigned short* __restrict__ encT,
                                              float* __restrict__ attn_out,
                                              unsigned short* __restrict__ lstmin){
  const int b = blockIdx.x;
  const int tid = threadIdx.x;
  const int wave = tid >> 6, lane = tid & 63;
  const int l15 = lane & 15, quad = lane >> 4;
  __shared__ unsigned short AB[2][64][136];
  __shared__ float ss[64][66];
  __shared__ unsigned short Ps[64][72];

  f32x4 acc[4] = {};
  for (int kc = 0; kc < 4; kc++){
    int k0 = kc * 128;
    #pragma unroll
    for (int i = 0; i < 4; i++){
      int idx = i * 256 + tid;
      int row = idx >> 4, ch = (idx & 15) * 8;
      *(s16x8*)&AB[0][row][ch] = *(const s16x8*)&q[(b*64 + row) * DU + k0 + ch];
      *(s16x8*)&AB[1][row][ch] = *(const s16x8*)&enc_bf[(b*64 + row) * DU + k0 + ch];
    }
    __syncthreads();
    #pragma unroll
    for (int ks = 0; ks < 4; ks++){
      s16x8 a = *(const s16x8*)&AB[0][wave*16 + l15][ks*32 + quad*8];
      #pragma unroll
      for (int nt = 0; nt < 4; nt++){
        s16x8 bb = *(const s16x8*)&AB[1][nt*16 + l15][ks*32 + quad*8];
        acc[nt] = __builtin_amdgcn_mfma_f32_16x16x32_bf16(a, bb, acc[nt], 0, 0, 0);
      }
    }
    __syncthreads();
  }
  #pragma unroll
  for (int nt = 0; nt < 4; nt++)
    #pragma unroll
    for (int r = 0; r < 4; r++)
      ss[wave*16 + quad*4 + r][nt*16 + l15] = acc[nt][r];
  __syncthreads();
  if (tid < 64){
    float mx = -1e30f;
    for (int s = 0; s < 64; s++) mx = fmaxf(mx, ss[tid][s]);
    float sum = 0.f;
    for (int s = 0; s < 64; s++){ float e = __expf(ss[tid][s] - mx); ss[tid][s] = e; sum += e; }
    float inv = 1.f / sum;
    for (int s = 0; s < 64; s++){
      float p = ss[tid][s] * inv;
      attn_out[(b*64 + tid) * 64 + s] = p;
      Ps[tid][s] = f2bf(p);
    }
  }
  __syncthreads();
  unsigned short (*B2)[72] = (unsigned short (*)[72])AB;
  for (int dc = 0; dc < 4; dc++){
    #pragma unroll
    for (int i = 0; i < 4; i++){
      int idx = i * 256 + tid;
      int row = idx >> 3, ch = (idx & 7) * 8;
      *(s16x8*)&B2[row][ch] = *(const s16x8*)&encT[(b*DU + dc*128 + row) * TIN + ch];
    }
    __syncthreads();
    f32x4 acc2[8] = {};
    #pragma unroll
    for (int ks = 0; ks < 2; ks++){
      s16x8 a = *(const s16x8*)&Ps[wave*16 + l15][ks*32 + quad*8];
      #pragma unroll
      for (int nt = 0; nt < 8; nt++){
        s16x8 bb = *(const s16x8*)&B2[nt*16 + l15][ks*32 + quad*8];
        acc2[nt] = __builtin_amdgcn_mfma_f32_16x16x32_bf16(a, bb, acc2[nt], 0, 0, 0);
      }
    }
    #pragma unroll
    for (int nt = 0; nt < 8; nt++){
      int d = dc*128 + nt*16 + l15;
      #pragma unroll
      for (int r = 0; r < 4; r++){
        int t = wave*16 + quad*4 + r;
        lstmin[(b*64 + t) * KL + d] = f2bf(acc2[nt][r]);
      }
    }
    __syncthreads();
  }
}

// ---------------- sequential LSTM: 16 WGs x 512 threads, Wh in registers ----------------
// WG wg owns hidden cols wg*32..wg*32+31 (z-cols n = g*32+j -> global g*512+wg*32+j).
// Per step: stage full h (32x512 bf16) global->LDS (xor-swizzled), MFMA vs register B-frags,
// gates, publish h slice, 16-WG barrier at L3 coherence point.
__global__ __launch_bounds__(512) void k_lstm(const float* __restrict__ Z,
                                              const unsigned short* __restrict__ Wh_t,
                                              const float* __restrict__ c0,
                                              unsigned short* __restrict__ hbuf,
                                              unsigned short* __restrict__ hs,
                                              float* __restrict__ out_h, float* __restrict__ out_c,
                                              unsigned int* __restrict__ cnt){
  const int wg = blockIdx.x;
  const int tid = threadIdx.x;
  const int wave = tid >> 6, lane = tid & 63;
  const int l15 = lane & 15, quad = lane >> 4;
  __shared__ unsigned short hlds[32 * 64 * 8];  // 32 rows x 64 16B-chunks, chunk kc at kc^(row&7)
  __shared__ float zs[32][132];

  // B fragments in registers: wave = n-tile (0..7), col n = wave*16+l15
  const int n = wave * 16 + l15;
  const int whrow = (n >> 5) * DU + wg * 32 + (n & 31);   // row in Wh_t[G4][DU]
  s16x8 bfr[16];
  #pragma unroll
  for (int ks = 0; ks < 16; ks++)
    bfr[ks] = *(const s16x8*)&Wh_t[(size_t)whrow * DU + ks*32 + quad*8];

  // gate-thread mapping: b = tid>>4, handles cols j=tid&15 and j+16
  const int gb = tid >> 4, gj = tid & 15;
  const int cbase = gb * DU + wg * 32 + gj;
  float c_a = c0[cbase];
  float c_b = c0[cbase + 16];

  float zv[8];
  {
    const float* zrow = Z + ((size_t)gb * 64 + 0) * G4 + wg * 32;
    #pragma unroll
    for (int g = 0; g < 4; g++){ zv[g] = zrow[g*DU + gj]; zv[4+g] = zrow[g*DU + 16 + gj]; }
  }

  for (int t = 0; t < 64; t++){
    // stage h(t): global (coherent, post-acquire) -> LDS, swizzled
    const unsigned short* hcur = hbuf + (t & 1) * NB * DU;
    #pragma unroll
    for (int i = 0; i < 4; i++){
      int chunk = i * 512 + tid;          // 0..2047
      int b = chunk >> 6, kc = chunk & 63;
      *(s16x8*)&hlds[(b * 64 + (kc ^ (b & 7))) * 8] = *(const s16x8*)&hcur[chunk * 8];
    }
    __syncthreads();

    f32x4 acc0 = {}, acc1 = {};
    #pragma unroll
    for (int ks = 0; ks < 16; ks++){
      int kc = ks * 4 + quad;
      int b0 = l15, b1 = 16 + l15;
      s16x8 a0 = *(const s16x8*)&hlds[(b0 * 64 + (kc ^ (b0 & 7))) * 8];
      s16x8 a1 = *(const s16x8*)&hlds[(b1 * 64 + (kc ^ (b1 & 7))) * 8];
      acc0 = __builtin_amdgcn_mfma_f32_16x16x32_bf16(a0, bfr[ks], acc0, 0, 0, 0);
      acc1 = __builtin_amdgcn_mfma_f32_16x16x32_bf16(a1, bfr[ks], acc1, 0, 0, 0);
    }
    #pragma unroll
    for (int r = 0; r < 4; r++){
      zs[quad*4 + r][wave*16 + l15]      = acc0[r];
      zs[16 + quad*4 + r][wave*16 + l15] = acc1[r];
    }
    __syncthreads();

    { // gates for (gb, gj) and (gb, gj+16)
      float h_a, h_b;
      {
        float zi = zs[gb][0  + gj] + zv[0], zf = zs[gb][32 + gj] + zv[1];
        float zg = zs[gb][64 + gj] + zv[2], zo = zs[gb][96 + gj] + zv[3];
        float gi = 1.f / (1.f + __expf(-zi));
        float gf = 1.f / (1.f + __expf(-zf));
        float e2 = __expf(2.f * zg); float gc = (e2 - 1.f) / (e2 + 1.f);
        float go = 1.f / (1.f + __expf(-zo));
        c_a = gf * c_a + gi * gc;
        float ec = __expf(2.f * c_a); float tc = (ec - 1.f) / (ec + 1.f);
        h_a = go * tc;
      }
      {
        float zi = zs[gb][16  + gj] + zv[4], zf = zs[gb][48 + gj] + zv[5];
        float zg = zs[gb][80 + gj] + zv[6], zo = zs[gb][112 + gj] + zv[7];
        float gi = 1.f / (1.f + __expf(-zi));
        float gf = 1.f / (1.f + __expf(-zf));
        float e2 = __expf(2.f * zg); float gc = (e2 - 1.f) / (e2 + 1.f);
        float go = 1.f / (1.f + __expf(-zo));
        c_b = gf * c_b + gi * gc;
        float ec = __expf(2.f * c_b); float tc = (ec - 1.f) / (ec + 1.f);
        h_b = go * tc;
      }
      unsigned short ha = f2bf(h_a), hb = f2bf(h_b);
      unsigned short* hnext = hbuf + ((t + 1) & 1) * NB * DU;
      hnext[cbase] = ha;
      hnext[cbase + 16] = hb;
      size_t hsrow = ((size_t)gb * 64 + t) * DU + wg * 32 + gj;
      hs[hsrow] = ha;
      hs[hsrow + 16] = hb;
      if (t == 63){
        out_h[cbase] = h_a; out_h[cbase + 16] = h_b;
        out_c[cbase] = c_a; out_c[cbase + 16] = c_b;
      }
    }

    if (t < 63){
      // prefetch Z for next step (no dependence on h)
      const float* zrow = Z + ((size_t)gb * 64 + t + 1) * G4 + wg * 32;
      #pragma unroll
      for (int g = 0; g < 4; g++){ zv[g] = zrow[g*DU + gj]; zv[4+g] = zrow[g*DU + 16 + gj]; }
      __syncthreads();   // all waves' h stores drained (vmcnt0) before release
      if (tid == 0){
        __hip_atomic_fetch_add(cnt, 1u, __ATOMIC_RELEASE, __HIP_MEMORY_SCOPE_AGENT);
        unsigned int target = 16u * (unsigned)(t + 1);
        while (__hip_atomic_load(cnt, __ATOMIC_RELAXED, __HIP_MEMORY_SCOPE_AGENT) < target)
          __builtin_amdgcn_s_sleep(1);
        __builtin_amdgcn_fence(__ATOMIC_ACQUIRE, "agent");
      }
      __syncthreads();
    }
  }
}

extern "C" void kernel_launch(void* const* d_in, const int* in_sizes, int n_in,
                              void* d_out, int out_size, void* d_ws, size_t ws_size,
                              hipStream_t stream) {
  const int*   toks   = (const int*)  d_in[0];
  const float* enc    = (const float*)d_in[1];
  const float* h0     = (const float*)d_in[2];
  const float* c0     = (const float*)d_in[3];
  const float* emb    = (const float*)d_in[4];
  const float* Wq     = (const float*)d_in[5];
  const float* bq     = (const float*)d_in[6];
  const float* Wx     = (const float*)d_in[7];
  const float* Wh     = (const float*)d_in[8];
  const float* b_lstm = (const float*)d_in[9];
  const float* Wfc    = (const float*)d_in[10];
  const float* bfc    = (const float*)d_in[11];

  float* out_logits = (float*)d_out;
  float* out_h    = out_logits + (size_t)BT * VSZ;
  float* out_c    = out_h + NB * DU;
  float* out_attn = out_c + NB * DU;

  char* ws = (char*)d_ws;
  size_t off = 0;
  auto take = [&](size_t bytes){ void* p = ws + off; off += (bytes + 255) & ~(size_t)255; return p; };
  unsigned int*   cnt    = (unsigned int*)  take(256);
  unsigned short* x_bf   = (unsigned short*)take((size_t)BT * EMB * 2);
  unsigned short* lstmin = (unsigned short*)take((size_t)BT * KL * 2);
  unsigned short* q_bf   = (unsigned short*)take((size_t)BT * DU * 2);
  unsigned short* enc_bf = (unsigned short*)take((size_t)NB * TIN * DU * 2);
  unsigned short* encT   = (unsigned short*)take((size_t)NB * DU * TIN * 2);
  unsigned short* Wq_t   = (unsigned short*)take((size_t)DU * EMB * 2);
  unsigned short* Wx_t   = (unsigned short*)take((size_t)G4 * KL * 2);
  unsigned short* Wh_t   = (unsigned short*)take((size_t)G4 * DU * 2);
  unsigned short* Wfc_t  = (unsigned short*)take((size_t)VSZ * DU * 2);
  float*          Zbuf   = (float*)         take((size_t)BT * G4 * 4);
  unsigned short* hbuf   = (unsigned short*)take((size_t)2 * NB * DU * 2);
  unsigned short* hs     = (unsigned short*)take((size_t)BT * DU * 2);

  hipMemsetAsync(cnt, 0, 256, stream);

  k_embed<<<BT * EMB / 256, 256, 0, stream>>>(toks, emb, x_bf, lstmin);
  k_h0cast<<<NB * DU / 256, 256, 0, stream>>>(h0, hbuf);
  k_enccast<<<dim3(DU/32, TIN/32, NB), 256, 0, stream>>>(enc, enc_bf, encT);
  k_transpose<<<dim3(DU/32, EMB/32), 256, 0, stream>>>(Wq, Wq_t, EMB, DU);
  k_transpose<<<dim3(G4/32, KL/32), 256, 0, stream>>>(Wx, Wx_t, KL, G4);
  k_transpose<<<dim3(G4/32, DU/32), 256, 0, stream>>>(Wh, Wh_t, DU, G4);
  k_transpose<<<dim3(VSZ/32, DU/32), 256, 0, stream>>>(Wfc, Wfc_t, DU, VSZ);

  // q = x @ Wq + bq  -> bf16
  k_gemm_bt<true, true><<<dim3(DU/128, BT/128), 256, 0, stream>>>(x_bf, Wq_t, bq, q_bf, BT, DU, EMB);
  // attention -> lstmin cols [0,DU), attn_w -> d_out
  k_attn<<<NB, 256, 0, stream>>>(q_bf, enc_bf, encT, out_attn, lstmin);
  // Z = lstm_in @ Wx + b_lstm  -> fp32
  k_gemm_bt<false, true><<<dim3(G4/128, BT/128), 256, 0, stream>>>(lstmin, Wx_t, b_lstm, Zbuf, BT, G4, KL);
  // sequential LSTM (16 co-resident WGs, manual grid barrier)
  k_lstm<<<16, 512, 0, stream>>>(Zbuf, Wh_t, c0, hbuf, hs, out_h, out_c, cnt);
  // logits = hs @ Wfc + bfc -> fp32 d_out (m97-style staging)
  k_gemm_lds<<<dim3(VSZ/128, BT/128), 256, 0, stream>>>(hs, Wfc_t, bfc, out_logits, BT, VSZ, DU);
}

// Round 3
// 745.066 us; speedup vs baseline: 1.8253x; 1.0107x over previous
//
#include <hip/hip_runtime.h>
#include <cstdint>

#define NB 32      // batch
#define TIN 64
#define TOUT 64
#define EMB 256
#define DU 512
#define VSZ 32000
#define BT 2048    // NB*TOUT
#define G4 2048    // 4*DU
#define KL 768     // DU+EMB

typedef __attribute__((ext_vector_type(4))) float f32x4;
typedef __attribute__((ext_vector_type(8))) short s16x8;
typedef __attribute__((ext_vector_type(4))) unsigned int u32x4;

__device__ __forceinline__ unsigned short f2bf(float f){
  unsigned int u = __float_as_uint(f);
  u += 0x7fffu + ((u >> 16) & 1u);
  return (unsigned short)(u >> 16);
}

// device-coherent (Infinity-Cache point) 16B accesses — bypass the non-coherent
// per-XCD L2 path for cross-WG h exchange; no fence cache-ops needed.
__device__ __forceinline__ void store16_sc(void* p, u32x4 v){
  asm volatile("global_store_dwordx4 %0, %1, off sc0 sc1" :: "v"(p), "v"(v) : "memory");
}
__device__ __forceinline__ u32x4 load16_sc(const void* p){
  u32x4 r;
  asm volatile("global_load_dwordx4 %0, %1, off sc0 sc1" : "=v"(r) : "v"(p) : "memory");
  return r;
}
__device__ __forceinline__ void vm_drain(){
  asm volatile("s_waitcnt vmcnt(0)" ::: "memory");
}

// ---------------- embedding gather + cast ----------------
__global__ void k_embed(const int* __restrict__ toks, const float* __restrict__ emb,
                        unsigned short* __restrict__ x_bf, unsigned short* __restrict__ lstmin){
  int idx = blockIdx.x * 256 + threadIdx.x;   // 0..BT*EMB-1
  int row = idx >> 8, e = idx & 255;
  int tok = toks[row];
  unsigned short h = f2bf(emb[tok * EMB + e]);
  x_bf[row * EMB + e] = h;
  lstmin[row * KL + DU + e] = h;   // x occupies cols [DU, DU+EMB)
}

// ---------------- h0 fp32 -> bf16 into hbuf slot 0 ----------------
__global__ void k_h0cast(const float* __restrict__ h0, unsigned short* __restrict__ hbuf){
  int i = blockIdx.x * 256 + threadIdx.x;
  hbuf[i] = f2bf(h0[i]);
}

// ---------------- enc cast + per-batch transpose ----------------
__global__ void k_enccast(const float* __restrict__ enc, unsigned short* __restrict__ enc_bf,
                          unsigned short* __restrict__ encT){
  int b = blockIdx.z, dt = blockIdx.x, st = blockIdx.y;
  __shared__ float tile[32][33];
  int tx = threadIdx.x & 31, ty = threadIdx.x >> 5;
  const float* eb = enc + b * TIN * DU;
  #pragma unroll
  for (int i = 0; i < 4; i++){
    int s = st*32 + ty + i*8, d = dt*32 + tx;
    float v = eb[s * DU + d];
    tile[ty + i*8][tx] = v;
    enc_bf[(b * TIN + s) * DU + d] = f2bf(v);
  }
  __syncthreads();
  #pragma unroll
  for (int i = 0; i < 4; i++){
    int d = dt*32 + ty + i*8, s = st*32 + tx;
    encT[(b * DU + d) * TIN + s] = f2bf(tile[tx][ty + i*8]);
  }
}

// ---------------- fp32 [R][C] -> bf16 [C][R] transpose ----------------
__global__ void k_transpose(const float* __restrict__ in, unsigned short* __restrict__ out, int R, int C){
  __shared__ float tile[32][33];
  int tx = threadIdx.x & 31, ty = threadIdx.x >> 5;
  int c0 = blockIdx.x * 32, r0 = blockIdx.y * 32;
  #pragma unroll
  for (int i = 0; i < 4; i++) tile[ty + i*8][tx] = in[(r0 + ty + i*8) * C + c0 + tx];
  __syncthreads();
  #pragma unroll
  for (int i = 0; i < 4; i++) out[(c0 + ty + i*8) * R + r0 + tx] = f2bf(tile[tx][ty + i*8]);
}

// ---------------- generic bf16 GEMM (padded-LDS variant): C[M,N]=A[M,K]*Bt[N,K]^T ----------------
template<bool OUT_BF16, bool BIAS>
__global__ __launch_bounds__(256) void k_gemm_bt(const unsigned short* __restrict__ A,
                                                 const unsigned short* __restrict__ Bt,
                                                 const float* __restrict__ bias,
                                                 void* __restrict__ Cout, int M, int N, int K){
  __shared__ unsigned short As[128][72];
  __shared__ unsigned short Bs[128][72];
  const int tid = threadIdx.x;
  const int wave = tid >> 6, lane = tid & 63;
  const int l15 = lane & 15, quad = lane >> 4;
  const int m_base = blockIdx.y * 128, n_base = blockIdx.x * 128;
  const int wr = wave >> 1, wc = wave & 1;
  f32x4 acc[4][4] = {};
  const int srow = tid >> 3, schunk = (tid & 7) * 8;
  for (int k0 = 0; k0 < K; k0 += 64){
    #pragma unroll
    for (int rr = 0; rr < 4; rr++){
      int r = rr * 32 + srow;
      *(s16x8*)&As[r][schunk] = *(const s16x8*)&A[(size_t)(m_base + r) * K + k0 + schunk];
      *(s16x8*)&Bs[r][schunk] = *(const s16x8*)&Bt[(size_t)(n_base + r) * K + k0 + schunk];
    }
    __syncthreads();
    #pragma unroll
    for (int ks = 0; ks < 2; ks++){
      s16x8 af[4], bfm[4];
      #pragma unroll
      for (int mt = 0; mt < 4; mt++) af[mt]  = *(const s16x8*)&As[wr*64 + mt*16 + l15][ks*32 + quad*8];
      #pragma unroll
      for (int nt = 0; nt < 4; nt++) bfm[nt] = *(const s16x8*)&Bs[wc*64 + nt*16 + l15][ks*32 + quad*8];
      #pragma unroll
      for (int mt = 0; mt < 4; mt++)
        #pragma unroll
        for (int nt = 0; nt < 4; nt++)
          acc[mt][nt] = __builtin_amdgcn_mfma_f32_16x16x32_bf16(af[mt], bfm[nt], acc[mt][nt], 0, 0, 0);
    }
    __syncthreads();
  }
  #pragma unroll
  for (int mt = 0; mt < 4; mt++){
    #pragma unroll
    for (int nt = 0; nt < 4; nt++){
      int n = n_base + wc*64 + nt*16 + l15;
      float bv = BIAS ? bias[n] : 0.f;
      #pragma unroll
      for (int r = 0; r < 4; r++){
        int m = m_base + wr*64 + mt*16 + quad*4 + r;
        float v = acc[mt][nt][r] + bv;
        if (OUT_BF16) ((unsigned short*)Cout)[(size_t)m * N + n] = f2bf(v);
        else          ((float*)Cout)[(size_t)m * N + n] = v;
      }
    }
  }
}

// ---------------- m97-style GEMM for logits: x = M-tiles (B-tile L2 reuse) ----------------
__global__ __launch_bounds__(256) void k_gemm_lds(const unsigned short* __restrict__ A,
                                                  const unsigned short* __restrict__ Bt,
                                                  const float* __restrict__ bias,
                                                  float* __restrict__ Cout, int M, int N, int K){
  __shared__ unsigned short As[128 * 64];
  __shared__ unsigned short Bs[128 * 64];
  const int tid = threadIdx.x;
  const int wave = tid >> 6, lane = tid & 63;
  const int l15 = lane & 15, quad = lane >> 4;
  const int m_base = blockIdx.x * 128, n_base = blockIdx.y * 128;
  const int wr = wave >> 1, wc = wave & 1;
  f32x4 acc[4][4] = {};
  const int srow = lane >> 3;        // 0..7 row within 8-row stripe
  const int scol = (lane & 7) * 8;   // short offset of 16B chunk
  for (int k0 = 0; k0 < K; k0 += 64){
    #pragma unroll
    for (int i = 0; i < 4; i++){
      int ra = wave * 32 + i * 8;    // stripe base row (wave-uniform)
      const unsigned short* ga = &A [(size_t)(m_base + ra + srow) * K + k0 + scol];
      const unsigned short* gb = &Bt[(size_t)(n_base + ra + srow) * K + k0 + scol];
      __builtin_amdgcn_global_load_lds((const __attribute__((address_space(1))) unsigned int*)ga,
                                       (__attribute__((address_space(3))) unsigned int*)&As[ra * 64],
                                       16, 0, 0);
      __builtin_amdgcn_global_load_lds((const __attribute__((address_space(1))) unsigned int*)gb,
                                       (__attribute__((address_space(3))) unsigned int*)&Bs[ra * 64],
                                       16, 0, 0);
    }
    __syncthreads();
    #pragma unroll
    for (int ks = 0; ks < 2; ks++){
      s16x8 af[4], bfm[4];
      #pragma unroll
      for (int mt = 0; mt < 4; mt++) af[mt]  = *(const s16x8*)&As[(wr*64 + mt*16 + l15) * 64 + ks*32 + quad*8];
      #pragma unroll
      for (int nt = 0; nt < 4; nt++) bfm[nt] = *(const s16x8*)&Bs[(wc*64 + nt*16 + l15) * 64 + ks*32 + quad*8];
      #pragma unroll
      for (int mt = 0; mt < 4; mt++)
        #pragma unroll
        for (int nt = 0; nt < 4; nt++)
          acc[mt][nt] = __builtin_amdgcn_mfma_f32_16x16x32_bf16(af[mt], bfm[nt], acc[mt][nt], 0, 0, 0);
    }
    __syncthreads();
  }
  #pragma unroll
  for (int mt = 0; mt < 4; mt++){
    #pragma unroll
    for (int nt = 0; nt < 4; nt++){
      int n = n_base + wc*64 + nt*16 + l15;
      float bv = bias[n];
      #pragma unroll
      for (int r = 0; r < 4; r++){
        int m = m_base + wr*64 + mt*16 + quad*4 + r;
        Cout[(size_t)m * N + n] = acc[mt][nt][r] + bv;
      }
    }
  }
}

// ---------------- fused attention per batch: scores -> softmax -> att ----------------
__global__ __launch_bounds__(256) void k_attn(const unsigned short* __restrict__ q,
                                              const unsigned short* __restrict__ enc_bf,
                                              const unsigned short* __restrict__ encT,
                                              float* __restrict__ attn_out,
                                              unsigned short* __restrict__ lstmin){
  const int b = blockIdx.x;
  const int tid = threadIdx.x;
  const int wave = tid >> 6, lane = tid & 63;
  const int l15 = lane & 15, quad = lane >> 4;
  __shared__ unsigned short AB[2][64][136];
  __shared__ float ss[64][66];
  __shared__ unsigned short Ps[64][72];

  f32x4 acc[4] = {};
  for (int kc = 0; kc < 4; kc++){
    int k0 = kc * 128;
    #pragma unroll
    for (int i = 0; i < 4; i++){
      int idx = i * 256 + tid;
      int row = idx >> 4, ch = (idx & 15) * 8;
      *(s16x8*)&AB[0][row][ch] = *(const s16x8*)&q[(b*64 + row) * DU + k0 + ch];
      *(s16x8*)&AB[1][row][ch] = *(const s16x8*)&enc_bf[(b*64 + row) * DU + k0 + ch];
    }
    __syncthreads();
    #pragma unroll
    for (int ks = 0; ks < 4; ks++){
      s16x8 a = *(const s16x8*)&AB[0][wave*16 + l15][ks*32 + quad*8];
      #pragma unroll
      for (int nt = 0; nt < 4; nt++){
        s16x8 bb = *(const s16x8*)&AB[1][nt*16 + l15][ks*32 + quad*8];
        acc[nt] = __builtin_amdgcn_mfma_f32_16x16x32_bf16(a, bb, acc[nt], 0, 0, 0);
      }
    }
    __syncthreads();
  }
  #pragma unroll
  for (int nt = 0; nt < 4; nt++)
    #pragma unroll
    for (int r = 0; r < 4; r++)
      ss[wave*16 + quad*4 + r][nt*16 + l15] = acc[nt][r];
  __syncthreads();
  if (tid < 64){
    float mx = -1e30f;
    for (int s = 0; s < 64; s++) mx = fmaxf(mx, ss[tid][s]);
    float sum = 0.f;
    for (int s = 0; s < 64; s++){ float e = __expf(ss[tid][s] - mx); ss[tid][s] = e; sum += e; }
    float inv = 1.f / sum;
    for (int s = 0; s < 64; s++){
      float p = ss[tid][s] * inv;
      attn_out[(b*64 + tid) * 64 + s] = p;
      Ps[tid][s] = f2bf(p);
    }
  }
  __syncthreads();
  unsigned short (*B2)[72] = (unsigned short (*)[72])AB;
  for (int dc = 0; dc < 4; dc++){
    #pragma unroll
    for (int i = 0; i < 4; i++){
      int idx = i * 256 + tid;
      int row = idx >> 3, ch = (idx & 7) * 8;
      *(s16x8*)&B2[row][ch] = *(const s16x8*)&encT[(b*DU + dc*128 + row) * TIN + ch];
    }
    __syncthreads();
    f32x4 acc2[8] = {};
    #pragma unroll
    for (int ks = 0; ks < 2; ks++){
      s16x8 a = *(const s16x8*)&Ps[wave*16 + l15][ks*32 + quad*8];
      #pragma unroll
      for (int nt = 0; nt < 8; nt++){
        s16x8 bb = *(const s16x8*)&B2[nt*16 + l15][ks*32 + quad*8];
        acc2[nt] = __builtin_amdgcn_mfma_f32_16x16x32_bf16(a, bb, acc2[nt], 0, 0, 0);
      }
    }
    #pragma unroll
    for (int nt = 0; nt < 8; nt++){
      int d = dc*128 + nt*16 + l15;
      #pragma unroll
      for (int r = 0; r < 4; r++){
        int t = wave*16 + quad*4 + r;
        lstmin[(b*64 + t) * KL + d] = f2bf(acc2[nt][r]);
      }
    }
    __syncthreads();
  }
}

// ---------------- sequential LSTM: 16 WGs x 512 threads ----------------
// h exchange via sc0/sc1 (IF$-coherent) 16B ops; RELAXED counter barrier, no fences.
__global__ __launch_bounds__(512) void k_lstm(const float* __restrict__ Z,
                                              const unsigned short* __restrict__ Wh_t,
                                              const float* __restrict__ c0,
                                              unsigned short* __restrict__ hbuf,
                                              unsigned short* __restrict__ hs,
                                              float* __restrict__ out_h, float* __restrict__ out_c,
                                              unsigned int* __restrict__ cnt){
  const int wg = blockIdx.x;
  const int tid = threadIdx.x;
  const int wave = tid >> 6, lane = tid & 63;
  const int l15 = lane & 15, quad = lane >> 4;
  __shared__ unsigned short hlds[32 * 64 * 8];  // 32 rows x 64 16B-chunks, chunk kc at kc^(row&7)
  __shared__ float zs[32][132];
  __shared__ unsigned short hstage[32 * 32];    // this WG's h slice, b-major

  // B fragments in registers: wave = n-tile (0..7), col n = wave*16+l15
  const int n = wave * 16 + l15;
  const int whrow = (n >> 5) * DU + wg * 32 + (n & 31);   // row in Wh_t[G4][DU]
  s16x8 bfr[16];
  #pragma unroll
  for (int ks = 0; ks < 16; ks++)
    bfr[ks] = *(const s16x8*)&Wh_t[(size_t)whrow * DU + ks*32 + quad*8];

  // gate-thread mapping: b = tid>>4, cols j=tid&15 and j+16
  const int gb = tid >> 4, gj = tid & 15;
  const int cbase = gb * DU + wg * 32 + gj;
  float c_a = c0[cbase];
  float c_b = c0[cbase + 16];

  // publish mapping (tid<128): b = tid>>2, 16B chunk = tid&3
  const int pb = tid >> 2, pch = tid & 3;

  float zv[8];
  {
    const float* zrow = Z + ((size_t)gb * 64 + 0) * G4 + wg * 32;
    #pragma unroll
    for (int g = 0; g < 4; g++){ zv[g] = zrow[g*DU + gj]; zv[4+g] = zrow[g*DU + 16 + gj]; }
  }

  for (int t = 0; t < 64; t++){
    // stage h(t): coherent loads -> LDS, xor-swizzled
    const unsigned short* hcur = hbuf + (t & 1) * NB * DU;
    u32x4 hv[4];
    #pragma unroll
    for (int i = 0; i < 4; i++) hv[i] = load16_sc(&hcur[(i * 512 + tid) * 8]);
    vm_drain();
    #pragma unroll
    for (int i = 0; i < 4; i++){
      int chunk = i * 512 + tid;
      int b = chunk >> 6, kc = chunk & 63;
      *(u32x4*)&hlds[(b * 64 + (kc ^ (b & 7))) * 8] = hv[i];
    }
    __syncthreads();

    f32x4 acc0 = {}, acc1 = {};
    #pragma unroll
    for (int ks = 0; ks < 16; ks++){
      int kc = ks * 4 + quad;
      int b0 = l15, b1 = 16 + l15;
      s16x8 a0 = *(const s16x8*)&hlds[(b0 * 64 + (kc ^ (b0 & 7))) * 8];
      s16x8 a1 = *(const s16x8*)&hlds[(b1 * 64 + (kc ^ (b1 & 7))) * 8];
      acc0 = __builtin_amdgcn_mfma_f32_16x16x32_bf16(a0, bfr[ks], acc0, 0, 0, 0);
      acc1 = __builtin_amdgcn_mfma_f32_16x16x32_bf16(a1, bfr[ks], acc1, 0, 0, 0);
    }
    #pragma unroll
    for (int r = 0; r < 4; r++){
      zs[quad*4 + r][wave*16 + l15]      = acc0[r];
      zs[16 + quad*4 + r][wave*16 + l15] = acc1[r];
    }
    __syncthreads();

    { // gates for (gb, gj) and (gb, gj+16)
      float h_a, h_b;
      {
        float zi = zs[gb][0  + gj] + zv[0], zf = zs[gb][32 + gj] + zv[1];
        float zg = zs[gb][64 + gj] + zv[2], zo = zs[gb][96 + gj] + zv[3];
        float gi = 1.f / (1.f + __expf(-zi));
        float gf = 1.f / (1.f + __expf(-zf));
        float e2 = __expf(2.f * zg); float gc = (e2 - 1.f) / (e2 + 1.f);
        float go = 1.f / (1.f + __expf(-zo));
        c_a = gf * c_a + gi * gc;
        float ec = __expf(2.f * c_a); float tc = (ec - 1.f) / (ec + 1.f);
        h_a = go * tc;
      }
      {
        float zi = zs[gb][16  + gj] + zv[4], zf = zs[gb][48 + gj] + zv[5];
        float zg = zs[gb][80 + gj] + zv[6], zo = zs[gb][112 + gj] + zv[7];
        float gi = 1.f / (1.f + __expf(-zi));
        float gf = 1.f / (1.f + __expf(-zf));
        float e2 = __expf(2.f * zg); float gc = (e2 - 1.f) / (e2 + 1.f);
        float go = 1.f / (1.f + __expf(-zo));
        c_b = gf * c_b + gi * gc;
        float ec = __expf(2.f * c_b); float tc = (ec - 1.f) / (ec + 1.f);
        h_b = go * tc;
      }
      hstage[gb * 32 + gj]      = f2bf(h_a);
      hstage[gb * 32 + 16 + gj] = f2bf(h_b);
      if (t == 63){
        out_h[cbase] = h_a; out_h[cbase + 16] = h_b;
        out_c[cbase] = c_a; out_c[cbase + 16] = c_b;
      }
    }
    __syncthreads();

    // publish: 128 threads, 16B vector stores (coherent for hnext, plain for hs)
    if (tid < 128){
      u32x4 v = *(const u32x4*)&hstage[pb * 32 + pch * 8];
      if (t < 63){
        unsigned short* hnext = hbuf + ((t + 1) & 1) * NB * DU;
        store16_sc(&hnext[pb * DU + wg * 32 + pch * 8], v);
      }
      *(u32x4*)&hs[((size_t)pb * 64 + t) * DU + wg * 32 + pch * 8] = v;
      vm_drain();
    }

    if (t < 63){
      // prefetch Z for next step (plain loads, read-only data)
      const float* zrow = Z + ((size_t)gb * 64 + t + 1) * G4 + wg * 32;
      #pragma unroll
      for (int g = 0; g < 4; g++){ zv[g] = zrow[g*DU + gj]; zv[4+g] = zrow[g*DU + 16 + gj]; }
      __syncthreads();   // publishing waves' stores drained before release add
      if (tid == 0){
        __hip_atomic_fetch_add(cnt, 1u, __ATOMIC_RELAXED, __HIP_MEMORY_SCOPE_AGENT);
        unsigned int target = 16u * (unsigned)(t + 1);
        while (__hip_atomic_load(cnt, __ATOMIC_RELAXED, __HIP_MEMORY_SCOPE_AGENT) < target)
          __builtin_amdgcn_s_sleep(1);
      }
      __syncthreads();
    }
  }
}

extern "C" void kernel_launch(void* const* d_in, const int* in_sizes, int n_in,
                              void* d_out, int out_size, void* d_ws, size_t ws_size,
                              hipStream_t stream) {
  const int*   toks   = (const int*)  d_in[0];
  const float* enc    = (const float*)d_in[1];
  const float* h0     = (const float*)d_in[2];
  const float* c0     = (const float*)d_in[3];
  const float* emb    = (const float*)d_in[4];
  const float* Wq     = (const float*)d_in[5];
  const float* bq     = (const float*)d_in[6];
  const float* Wx     = (const float*)d_in[7];
  const float* Wh     = (const float*)d_in[8];
  const float* b_lstm = (const float*)d_in[9];
  const float* Wfc    = (const float*)d_in[10];
  const float* bfc    = (const float*)d_in[11];

  float* out_logits = (float*)d_out;
  float* out_h    = out_logits + (size_t)BT * VSZ;
  float* out_c    = out_h + NB * DU;
  float* out_attn = out_c + NB * DU;

  char* ws = (char*)d_ws;
  size_t off = 0;
  auto take = [&](size_t bytes){ void* p = ws + off; off += (bytes + 255) & ~(size_t)255; return p; };
  unsigned int*   cnt    = (unsigned int*)  take(256);
  unsigned short* x_bf   = (unsigned short*)take((size_t)BT * EMB * 2);
  unsigned short* lstmin = (unsigned short*)take((size_t)BT * KL * 2);
  unsigned short* q_bf   = (unsigned short*)take((size_t)BT * DU * 2);
  unsigned short* enc_bf = (unsigned short*)take((size_t)NB * TIN * DU * 2);
  unsigned short* encT   = (unsigned short*)take((size_t)NB * DU * TIN * 2);
  unsigned short* Wq_t   = (unsigned short*)take((size_t)DU * EMB * 2);
  unsigned short* Wx_t   = (unsigned short*)take((size_t)G4 * KL * 2);
  unsigned short* Wh_t   = (unsigned short*)take((size_t)G4 * DU * 2);
  unsigned short* Wfc_t  = (unsigned short*)take((size_t)VSZ * DU * 2);
  float*          Zbuf   = (float*)         take((size_t)BT * G4 * 4);
  unsigned short* hbuf   = (unsigned short*)take((size_t)2 * NB * DU * 2);
  unsigned short* hs     = (unsigned short*)take((size_t)BT * DU * 2);

  hipMemsetAsync(cnt, 0, 256, stream);

  k_embed<<<BT * EMB / 256, 256, 0, stream>>>(toks, emb, x_bf, lstmin);
  k_h0cast<<<NB * DU / 256, 256, 0, stream>>>(h0, hbuf);
  k_enccast<<<dim3(DU/32, TIN/32, NB), 256, 0, stream>>>(enc, enc_bf, encT);
  k_transpose<<<dim3(DU/32, EMB/32), 256, 0, stream>>>(Wq, Wq_t, EMB, DU);
  k_transpose<<<dim3(G4/32, KL/32), 256, 0, stream>>>(Wx, Wx_t, KL, G4);
  k_transpose<<<dim3(G4/32, DU/32), 256, 0, stream>>>(Wh, Wh_t, DU, G4);
  k_transpose<<<dim3(VSZ/32, DU/32), 256, 0, stream>>>(Wfc, Wfc_t, DU, VSZ);

  // q = x @ Wq + bq  -> bf16
  k_gemm_bt<true, true><<<dim3(DU/128, BT/128), 256, 0, stream>>>(x_bf, Wq_t, bq, q_bf, BT, DU, EMB);
  // attention -> lstmin cols [0,DU), attn_w -> d_out
  k_attn<<<NB, 256, 0, stream>>>(q_bf, enc_bf, encT, out_attn, lstmin);
  // Z = lstm_in @ Wx + b_lstm  -> fp32
  k_gemm_bt<false, true><<<dim3(G4/128, BT/128), 256, 0, stream>>>(lstmin, Wx_t, b_lstm, Zbuf, BT, G4, KL);
  // sequential LSTM (16 co-resident WGs, relaxed counter barrier)
  k_lstm<<<16, 512, 0, stream>>>(Zbuf, Wh_t, c0, hbuf, hs, out_h, out_c, cnt);
  // logits = hs @ Wfc + bfc -> fp32 d_out (x = M-tiles for B-tile L2 reuse)
  k_gemm_lds<<<dim3(BT/128, VSZ/128), 256, 0, stream>>>(hs, Wfc_t, bfc, out_logits, BT, VSZ, DU);
}